// Round 9
// baseline (1060.518 us; speedup 1.0000x reference)
//
#include <hip/hip_runtime.h>
#include <hip/hip_bf16.h>
#include <hip/hip_cooperative_groups.h>
#include <cstdint>
#include <cstddef>

namespace cg = cooperative_groups;

#define D 256

typedef __attribute__((ext_vector_type(8))) short bf16x8;
typedef __attribute__((ext_vector_type(4))) float f32x4;
typedef __attribute__((ext_vector_type(4))) unsigned short ushort4v;
typedef __attribute__((ext_vector_type(8))) unsigned short ushort8v;

__device__ __forceinline__ unsigned short f2bf(float f) {  // RNE
  union { float f; unsigned int u; } v; v.f = f;
  unsigned int u = v.u;
  u += ((u >> 16) & 1u) + 0x7fffu;
  return (unsigned short)(u >> 16);
}
__device__ __forceinline__ float bf2f(unsigned short s) {
  union { unsigned int u; float f; } v; v.u = ((unsigned int)s) << 16;
  return v.f;
}

#define GLL16(g, l) __builtin_amdgcn_global_load_lds( \
    (const __attribute__((address_space(1))) void*)(g), \
    (__attribute__((address_space(3))) void*)(l), 16, 0, 0)

// ---------------- cooperative CSR build (replaces 6 dispatches) ----------------
// phases: zero deg -> atomic deg -> block partial sums -> 1-wave scan ->
//         block apply (row_ptr/cursor) -> fill col. grid.sync() between phases.

__global__ __launch_bounds__(256) void k_csr(const int* __restrict__ src,
                                             const int* __restrict__ dst,
                                             int* __restrict__ deg,
                                             int* __restrict__ row_ptr,
                                             int* __restrict__ cursor,
                                             int* __restrict__ col,
                                             int* __restrict__ bsum,
                                             int* __restrict__ boff,
                                             int M, int E, int nb) {
  cg::grid_group grid = cg::this_grid();
  __shared__ int sm[256];
  const int tid = threadIdx.x;
  const int bid = blockIdx.x;
  const int gsz = gridDim.x * 256;
  const int gtid = bid * 256 + tid;

  // phase 0: zero deg
  for (int i = gtid; i < M; i += gsz) deg[i] = 0;
  grid.sync();

  // phase 1: degree count
  for (int e = gtid; e < E; e += gsz) atomicAdd(&deg[dst[e]], 1);
  grid.sync();

  // phase 2: per-block partial sums over 1024-elem chunks
  if (bid < nb) {
    int base = bid * 1024 + tid * 4;
    int s = 0;
#pragma unroll
    for (int i = 0; i < 4; ++i) s += (base + i < M) ? deg[base + i] : 0;
    sm[tid] = s;
    __syncthreads();
    for (int off = 128; off > 0; off >>= 1) {
      if (tid < off) sm[tid] += sm[tid + off];
      __syncthreads();
    }
    if (tid == 0) bsum[bid] = sm[0];
  }
  grid.sync();

  // phase 3: single-wave exclusive scan of nb block sums
  if (bid == 0 && tid < 64) {
    int l = tid;
    int orig = (l < nb) ? bsum[l] : 0;
    int v = orig;
    for (int off = 1; off < 64; off <<= 1) {
      int t = __shfl_up(v, off);
      if (l >= off) v += t;
    }
    if (l < nb) boff[l] = v - orig;
    if (l == nb - 1) row_ptr[M] = v;
  }
  grid.sync();

  // phase 4: apply — block-wide exclusive scan of 1024 degs + block offset
  if (bid < nb) {
    int base = bid * 1024 + tid * 4;
    int d[4], p[4];
#pragma unroll
    for (int i = 0; i < 4; ++i) d[i] = (base + i < M) ? deg[base + i] : 0;
    p[0] = 0; p[1] = d[0]; p[2] = d[0] + d[1]; p[3] = d[0] + d[1] + d[2];
    int s = p[3] + d[3];
    sm[tid] = s;
    __syncthreads();
    for (int off = 1; off < 256; off <<= 1) {
      int t = (tid >= off) ? sm[tid - off] : 0;
      __syncthreads();
      sm[tid] += t;
      __syncthreads();
    }
    int excl = sm[tid] - s + boff[bid];
#pragma unroll
    for (int i = 0; i < 4; ++i) {
      if (base + i < M) {
        row_ptr[base + i] = excl + p[i];
        cursor[base + i] = excl + p[i];
      }
    }
  }
  grid.sync();

  // phase 5: bucket fill
  for (int e = gtid; e < E; e += gsz) {
    int p = atomicAdd(&cursor[dst[e]], 1);
    col[p] = src[e];
  }
}

// ---------------- merged fp32 -> split-bf16 conversion (x + 5 weights) --------

__global__ __launch_bounds__(256) void k_splitall(
    const float* __restrict__ x, int nx4, int nxb,
    const float* __restrict__ W1l, const float* __restrict__ W1r,
    const float* __restrict__ W2l, const float* __restrict__ W2r,
    const float* __restrict__ Wm1,
    unsigned short* __restrict__ xh, unsigned short* __restrict__ xl,
    unsigned short* __restrict__ c1h, unsigned short* __restrict__ c1l,
    unsigned short* __restrict__ c2h, unsigned short* __restrict__ c2l,
    unsigned short* __restrict__ m1h, unsigned short* __restrict__ m1l) {
  const float* s; unsigned short* oh; unsigned short* ol; int i, lim;
  int bid = blockIdx.x;
  if (bid < nxb) {
    s = x; oh = xh; ol = xl;
    i = bid * 256 + threadIdx.x; lim = nx4;
  } else {
    int wb = bid - nxb;
    int w = wb >> 6;                       // 64 blocks per 256x256 matrix
    i = (wb & 63) * 256 + threadIdx.x; lim = 16384;
    switch (w) {
      case 0: s = W1l; oh = c1h;         ol = c1l;         break;
      case 1: s = W1r; oh = c1h + 65536; ol = c1l + 65536; break;
      case 2: s = W2l; oh = c2h;         ol = c2l;         break;
      case 3: s = W2r; oh = c2h + 65536; ol = c2l + 65536; break;
      default: s = Wm1; oh = m1h;        ol = m1l;         break;
    }
  }
  if (i >= lim) return;
  float4 v = ((const float4*)s)[i];
  float a[4] = {v.x, v.y, v.z, v.w};
  ushort4v h, l;
#pragma unroll
  for (int j = 0; j < 4; ++j) {
    h[j] = f2bf(a[j]);
    l[j] = f2bf(a[j] - bf2f(h[j]));
  }
  ((ushort4v*)oh)[i] = h;
  ((ushort4v*)ol)[i] = l;
}

// ---------------- split-bf16 MFMA GEMM (round-7 structure) ----------------
// C[M, NBF+NF] = (Ah+Al)[M,256] @ (Wh+Wl)[NBF+NF,256]^T  (3-term split product)
// 1-D grid, bijective XCD-chunk swizzle, bx fastest (A-tile L2 reuse).
// Double-buffered LDS with raw s_barrier + counted vmcnt(8).
// bf16 cols get +biasB & relu when biasB != null; f32 cols get +biasF (&relu).

__global__ __launch_bounds__(256) void k_gemm_mfma(
    const unsigned short* __restrict__ Ah, const unsigned short* __restrict__ Al,
    const unsigned short* __restrict__ Wh, const unsigned short* __restrict__ Wl,
    unsigned short* __restrict__ outBF, float* __restrict__ outF32,
    const float* __restrict__ biasF, const float* __restrict__ biasB,
    int M, int NBF, int NF, int relu, int nbxshift) {
  __shared__ char lds[65536];  // 2 buffers x (Ah 8K | Al 8K | Wh 8K | Wl 8K)

  const int tid = threadIdx.x;
  const int wave = tid >> 6;
  const int lane = tid & 63;

  // bijective XCD-chunk swizzle: consecutive logical ids run on one XCD.
  int nwg = gridDim.x;
  int id = blockIdx.x;
  int q = nwg >> 3, r = nwg & 7;
  int xcd = id & 7, j = id >> 3;
  int w = ((xcd < r) ? xcd * (q + 1) : r * (q + 1) + (xcd - r) * q) + j;
  const int by = w >> nbxshift;
  const int bx = w & ((1 << nbxshift) - 1);
  const int n0 = bx * 128;

  // staging: linear LDS dest (base + lane*16), global source pre-permuted
  // so that a read at logical k-slot g uses physical slot g ^ ((row>>1)&3).
  int aoff[2], woff[2], ldso[2];
#pragma unroll
  for (int rr = 0; rr < 2; ++rr) {
    int o = rr * 4096 + wave * 1024 + lane * 16;  // byte offset in tile
    int row = o >> 6;                             // 64 B per row (32 bf16)
    int sp = (o >> 4) & 3;                        // physical 16B slot
    int sl = sp ^ ((row >> 1) & 3);               // logical k-slot stored here
    int arow = by * 128 + row; if (arow > M - 1) arow = M - 1;
    aoff[rr] = arow * 256 + sl * 8;               // elements
    woff[rr] = (n0 + row) * 256 + sl * 8;
    ldso[rr] = rr * 4096 + wave * 1024;           // wave-uniform LDS base
  }

  const int rbase = (wave >> 1) * 64;
  const int cbase = (wave & 1) * 64;
  const int fr = lane & 15;
  const int g = lane >> 4;

  int a_addr[4], w_addr[4];
#pragma unroll
  for (int m = 0; m < 4; ++m) {
    int row = rbase + m * 16 + fr;
    a_addr[m] = row * 64 + ((g ^ ((row >> 1) & 3)) * 16);
  }
#pragma unroll
  for (int n = 0; n < 4; ++n) {
    int row = cbase + n * 16 + fr;
    w_addr[n] = row * 64 + ((g ^ ((row >> 1) & 3)) * 16);
  }

  f32x4 acc[4][4] = {};

  // prologue: stage step 0 into buffer 0
#pragma unroll
  for (int rr = 0; rr < 2; ++rr) {
    GLL16(Ah + aoff[rr], lds + 0     + ldso[rr]);
    GLL16(Al + aoff[rr], lds + 8192  + ldso[rr]);
    GLL16(Wh + woff[rr], lds + 16384 + ldso[rr]);
    GLL16(Wl + woff[rr], lds + 24576 + ldso[rr]);
  }

  for (int t = 0; t < 8; ++t) {
    const int cb = (t & 1) * 32768;        // current buffer
    if (t < 7) {
      const int nbuf = ((t + 1) & 1) * 32768;
      const int ko = (t + 1) * 32;
#pragma unroll
      for (int rr = 0; rr < 2; ++rr) {
        GLL16(Ah + aoff[rr] + ko, lds + nbuf + 0     + ldso[rr]);
        GLL16(Al + aoff[rr] + ko, lds + nbuf + 8192  + ldso[rr]);
        GLL16(Wh + woff[rr] + ko, lds + nbuf + 16384 + ldso[rr]);
        GLL16(Wl + woff[rr] + ko, lds + nbuf + 24576 + ldso[rr]);
      }
      asm volatile("s_waitcnt vmcnt(8)" ::: "memory");  // oldest 8 (cur buf) done
    } else {
      asm volatile("s_waitcnt vmcnt(0)" ::: "memory");
    }
    __builtin_amdgcn_s_barrier();          // all waves' cur-buf loads done

    bf16x8 ah[4], al[4], wh[4], wl[4];
#pragma unroll
    for (int m = 0; m < 4; ++m) {
      ah[m] = *(const bf16x8*)(lds + cb + 0    + a_addr[m]);
      al[m] = *(const bf16x8*)(lds + cb + 8192 + a_addr[m]);
    }
#pragma unroll
    for (int n = 0; n < 4; ++n) {
      wh[n] = *(const bf16x8*)(lds + cb + 16384 + w_addr[n]);
      wl[n] = *(const bf16x8*)(lds + cb + 24576 + w_addr[n]);
    }
#pragma unroll
    for (int m = 0; m < 4; ++m)
#pragma unroll
      for (int n = 0; n < 4; ++n) {
        acc[m][n] = __builtin_amdgcn_mfma_f32_16x16x32_bf16(ah[m], wh[n], acc[m][n], 0, 0, 0);
        acc[m][n] = __builtin_amdgcn_mfma_f32_16x16x32_bf16(ah[m], wl[n], acc[m][n], 0, 0, 0);
        acc[m][n] = __builtin_amdgcn_mfma_f32_16x16x32_bf16(al[m], wh[n], acc[m][n], 0, 0, 0);
      }
    __builtin_amdgcn_s_barrier();          // all waves done reading cur buf
  }

  // epilogue: C/D layout col=lane&15, row=(lane>>4)*4+reg — direct stores
  if (n0 < NBF) {
#pragma unroll
    for (int n = 0; n < 4; ++n) {
      int col = n0 + cbase + n * 16 + fr;
      float bvb = biasB ? biasB[col] : 0.f;
#pragma unroll
      for (int m = 0; m < 4; ++m) {
        f32x4 a = acc[m][n];
#pragma unroll
        for (int rr = 0; rr < 4; ++rr) {
          int row = by * 128 + rbase + m * 16 + g * 4 + rr;
          if (row < M) {
            float v = a[rr] + bvb;
            if (biasB) v = fmaxf(v, 0.f);
            outBF[(size_t)row * NBF + col] = f2bf(v);
          }
        }
      }
    }
  } else {
#pragma unroll
    for (int n = 0; n < 4; ++n) {
      int col = n0 + cbase + n * 16 + fr;
      int fcol = col - NBF;
      float bv = biasF ? biasF[fcol] : 0.f;
#pragma unroll
      for (int m = 0; m < 4; ++m) {
        f32x4 a = acc[m][n];
#pragma unroll
        for (int rr = 0; rr < 4; ++rr) {
          int row = by * 128 + rbase + m * 16 + g * 4 + rr;
          if (row < M) {
            float v = a[rr] + bv;
            if (relu) v = fmaxf(v, 0.f);
            outF32[(size_t)row * NF + fcol] = v;
          }
        }
      }
    }
  }
}

// ---------------- aggregation (round-7 structure) ----------------
// one wave per node; lanes split in 2 halves, 2-deep unroll -> 4 row-gathers
// in flight per wave. Combine halves via shfl_xor(32).

__global__ __launch_bounds__(256) void k_agg2(const unsigned short* __restrict__ T1,
                                              const float* __restrict__ T2,
                                              unsigned short* __restrict__ Hh,
                                              unsigned short* __restrict__ Hl,
                                              const int* __restrict__ row_ptr,
                                              const int* __restrict__ col, int M) {
  int wave = threadIdx.x >> 6, lane = threadIdx.x & 63;
  int n = blockIdx.x * 4 + wave;
  if (n >= M) return;
  int beg = row_ptr[n], end = row_ptr[n + 1];
  int half = lane >> 5, sl = lane & 31;
  float s[8] = {0.f, 0.f, 0.f, 0.f, 0.f, 0.f, 0.f, 0.f};
  int j = beg + half;
  for (; j + 2 < end; j += 4) {
    int i0 = col[j];
    int i1 = col[j + 2];
    ushort8v v0 = *(const ushort8v*)(T1 + (size_t)i0 * 256 + sl * 8);
    ushort8v v1 = *(const ushort8v*)(T1 + (size_t)i1 * 256 + sl * 8);
#pragma unroll
    for (int i = 0; i < 8; ++i) s[i] += bf2f(v0[i]) + bf2f(v1[i]);
  }
  for (; j < end; j += 2) {
    int i0 = col[j];
    ushort8v v0 = *(const ushort8v*)(T1 + (size_t)i0 * 256 + sl * 8);
#pragma unroll
    for (int i = 0; i < 8; ++i) s[i] += bf2f(v0[i]);
  }
#pragma unroll
  for (int i = 0; i < 8; ++i) s[i] += __shfl_xor(s[i], 32);
  int dg = end - beg;
  float inv = 1.0f / (float)(dg > 0 ? dg : 1);
  const float4* t2p = (const float4*)(T2 + (size_t)n * 256 + sl * 8);
  float4 ta = t2p[0], tb = t2p[1];
  float h[8];
  h[0] = fmaxf(s[0] * inv + ta.x, 0.f);
  h[1] = fmaxf(s[1] * inv + ta.y, 0.f);
  h[2] = fmaxf(s[2] * inv + ta.z, 0.f);
  h[3] = fmaxf(s[3] * inv + ta.w, 0.f);
  h[4] = fmaxf(s[4] * inv + tb.x, 0.f);
  h[5] = fmaxf(s[5] * inv + tb.y, 0.f);
  h[6] = fmaxf(s[6] * inv + tb.z, 0.f);
  h[7] = fmaxf(s[7] * inv + tb.w, 0.f);
  if (half == 0) {
    ushort8v hh;
#pragma unroll
    for (int i = 0; i < 8; ++i) hh[i] = f2bf(h[i]);
    *(ushort8v*)(Hh + (size_t)n * 256 + sl * 8) = hh;
  } else {
    ushort8v hl;
#pragma unroll
    for (int i = 0; i < 8; ++i) {
      unsigned short hi = f2bf(h[i]);
      hl[i] = f2bf(h[i] - bf2f(hi));
    }
    *(ushort8v*)(Hl + (size_t)n * 256 + sl * 8) = hl;
  }
}

// ---------------- final: out = softmax(H_bf16[M,256] @ Wm2[8,256]^T + bm2) ----

__global__ __launch_bounds__(256) void k_final(const unsigned short* __restrict__ H,
                                               const float* __restrict__ Wm2,
                                               const float* __restrict__ bm2,
                                               float* __restrict__ out, int M) {
  int node = blockIdx.x * 4 + (threadIdx.x >> 6);
  int lane = threadIdx.x & 63;
  if (node >= M) return;
  int o = lane >> 3;   // output 0..7
  int r = lane & 7;    // 32-elem k-slice
  const unsigned short* h = H + (size_t)node * D + r * 32;
  const float* w = Wm2 + (size_t)o * D + r * 32;
  float p = 0.f;
#pragma unroll
  for (int c = 0; c < 4; ++c) {
    ushort8v hv = ((const ushort8v*)h)[c];
    float4 w0 = ((const float4*)w)[c * 2];
    float4 w1 = ((const float4*)w)[c * 2 + 1];
    p += bf2f(hv[0]) * w0.x + bf2f(hv[1]) * w0.y + bf2f(hv[2]) * w0.z + bf2f(hv[3]) * w0.w;
    p += bf2f(hv[4]) * w1.x + bf2f(hv[5]) * w1.y + bf2f(hv[6]) * w1.z + bf2f(hv[7]) * w1.w;
  }
  p += __shfl_xor(p, 1);
  p += __shfl_xor(p, 2);
  p += __shfl_xor(p, 4);
  float logit = p + bm2[o];
  float m = logit;
  m = fmaxf(m, __shfl_xor(m, 8));
  m = fmaxf(m, __shfl_xor(m, 16));
  m = fmaxf(m, __shfl_xor(m, 32));
  float e = expf(logit - m);
  float ssum = e;
  ssum += __shfl_xor(ssum, 8);
  ssum += __shfl_xor(ssum, 16);
  ssum += __shfl_xor(ssum, 32);
  if (r == 0) out[(size_t)node * 8 + o] = e / ssum;
}

// ---------------- launch ----------------

extern "C" void kernel_launch(void* const* d_in, const int* in_sizes, int n_in,
                              void* d_out, int out_size, void* d_ws, size_t ws_size,
                              hipStream_t stream) {
  const float* x   = (const float*)d_in[0];
  const int*   ei  = (const int*)d_in[1];
  const float* W1l = (const float*)d_in[2];
  const float* b1  = (const float*)d_in[3];
  const float* W1r = (const float*)d_in[4];
  const float* W2l = (const float*)d_in[5];
  const float* b2  = (const float*)d_in[6];
  const float* W2r = (const float*)d_in[7];
  const float* Wm1 = (const float*)d_in[8];
  const float* bm1 = (const float*)d_in[9];
  const float* Wm2 = (const float*)d_in[10];
  const float* bm2 = (const float*)d_in[11];
  float* out = (float*)d_out;

  int M = in_sizes[0] / D;   // 50000
  int E = in_sizes[1] / 2;   // 800000
  const int* src = ei;
  const int* dst = ei + E;

  char* p = (char*)d_ws;
  auto alloc = [&](size_t bytes) {
    char* q = p;
    p += (bytes + 255) & ~(size_t)255;
    return q;
  };
  unsigned short* bh0  = (unsigned short*)alloc((size_t)M * 256 * 2);  // x/h split hi
  unsigned short* bh1  = (unsigned short*)alloc((size_t)M * 256 * 2);  // x/h split lo
  unsigned short* T1bf = (unsigned short*)alloc((size_t)M * 256 * 2);  // neighbor-path / h3 (bf16)
  float*          T2f  = (float*)alloc((size_t)M * 256 * 4);           // root-path (f32)
  unsigned short* Wc1h = (unsigned short*)alloc(512 * 256 * 2);
  unsigned short* Wc1l = (unsigned short*)alloc(512 * 256 * 2);
  unsigned short* Wc2h = (unsigned short*)alloc(512 * 256 * 2);
  unsigned short* Wc2l = (unsigned short*)alloc(512 * 256 * 2);
  unsigned short* Wm1h = (unsigned short*)alloc(256 * 256 * 2);
  unsigned short* Wm1l = (unsigned short*)alloc(256 * 256 * 2);
  int* deg     = (int*)alloc((size_t)M * 4);
  int* row_ptr = (int*)alloc((size_t)(M + 1) * 4);
  int* cursor  = (int*)alloc((size_t)M * 4);
  int* col     = (int*)alloc((size_t)E * 4);
  int* bsum    = (int*)alloc(64 * 4);
  int* boff    = (int*)alloc(64 * 4);

  int nb = (M + 1023) / 1024;  // 49

  // cooperative CSR build (single dispatch; includes deg zeroing)
  {
    const int* srcv = src; const int* dstv = dst;
    int Mv = M, Ev = E, nbv = nb;
    void* args[] = {(void*)&srcv, (void*)&dstv, (void*)&deg, (void*)&row_ptr,
                    (void*)&cursor, (void*)&col, (void*)&bsum, (void*)&boff,
                    (void*)&Mv, (void*)&Ev, (void*)&nbv};
    hipLaunchCooperativeKernel((void*)k_csr, dim3(1024), dim3(256), args, 0, stream);
  }

  // merged split conversion (x + 5 weight matrices), single dispatch
  int nx4 = M * 256 / 4;               // 3.2M float4
  int nxb = (nx4 + 255) / 256;         // 12500 blocks for x
  k_splitall<<<dim3(nxb + 5 * 64), dim3(256), 0, stream>>>(
      x, nx4, nxb, W1l, W1r, W2l, W2r, Wm1,
      bh0, bh1, Wc1h, Wc1l, Wc2h, Wc2l, Wm1h, Wm1l);

  dim3 blk(256);
  int nwg4 = ((M + 127) / 128) * 4;  // 1564
  int nwg2 = ((M + 127) / 128) * 2;  // 782
  int aggGrid = (M + 3) / 4;

  // Layer 1: [T1 | T2] = x @ [W1l;W1r]^T ; h1 = relu(mean(T1)+T2+b1) -> bh0/bh1
  k_gemm_mfma<<<dim3(nwg4), blk, 0, stream>>>(bh0, bh1, Wc1h, Wc1l, T1bf, T2f,
                                              b1, nullptr, M, 256, 256, 0, 2);
  k_agg2<<<dim3(aggGrid), blk, 0, stream>>>(T1bf, T2f, bh0, bh1, row_ptr, col, M);
  // Layer 2
  k_gemm_mfma<<<dim3(nwg4), blk, 0, stream>>>(bh0, bh1, Wc2h, Wc2l, T1bf, T2f,
                                              b2, nullptr, M, 256, 256, 0, 2);
  k_agg2<<<dim3(aggGrid), blk, 0, stream>>>(T1bf, T2f, bh0, bh1, row_ptr, col, M);
  // MLP: h3 = relu(h2 @ Wm1^T + bm1) -> T1bf (bf16)
  k_gemm_mfma<<<dim3(nwg2), blk, 0, stream>>>(bh0, bh1, Wm1h, Wm1l, T1bf, nullptr,
                                              nullptr, bm1, M, 256, 0, 1, 1);
  // logits + softmax
  k_final<<<dim3((M + 3) / 4), blk, 0, stream>>>(T1bf, Wm2, bm2, out, M);
}

// Round 11
// 574.000 us; speedup vs baseline: 1.8476x; 1.8476x over previous
//
#include <hip/hip_runtime.h>
#include <hip/hip_bf16.h>
#include <cstdint>
#include <cstddef>

#define D 256

typedef __attribute__((ext_vector_type(8))) short bf16x8;
typedef __attribute__((ext_vector_type(4))) float f32x4;
typedef __attribute__((ext_vector_type(4))) unsigned short ushort4v;
typedef __attribute__((ext_vector_type(8))) unsigned short ushort8v;

__device__ __forceinline__ unsigned short f2bf(float f) {  // RNE
  union { float f; unsigned int u; } v; v.f = f;
  unsigned int u = v.u;
  u += ((u >> 16) & 1u) + 0x7fffu;
  return (unsigned short)(u >> 16);
}
__device__ __forceinline__ float bf2f(unsigned short s) {
  union { unsigned int u; float f; } v; v.u = ((unsigned int)s) << 16;
  return v.f;
}

#define GLL16(g, l) __builtin_amdgcn_global_load_lds( \
    (const __attribute__((address_space(1))) void*)(g), \
    (__attribute__((address_space(3))) void*)(l), 16, 0, 0)

// ---------------- CSR build (5 small dispatches — measured fast in r7/r8) ----

__global__ __launch_bounds__(256) void k_deg(const int* __restrict__ dst,
                                             int* __restrict__ deg, int E) {
  int e = blockIdx.x * 256 + threadIdx.x;
  if (e < E) atomicAdd(&deg[dst[e]], 1);
}

__global__ __launch_bounds__(256) void k_bsum(const int* __restrict__ deg,
                                              int* __restrict__ bsum, int M) {
  __shared__ int sm[256];
  int tid = threadIdx.x;
  int base = blockIdx.x * 1024 + tid * 4;
  int s = 0;
#pragma unroll
  for (int i = 0; i < 4; ++i) s += (base + i < M) ? deg[base + i] : 0;
  sm[tid] = s;
  __syncthreads();
  for (int off = 128; off > 0; off >>= 1) {
    if (tid < off) sm[tid] += sm[tid + off];
    __syncthreads();
  }
  if (tid == 0) bsum[blockIdx.x] = sm[0];
}

__global__ __launch_bounds__(64) void k_scanb(const int* __restrict__ bsum,
                                              int* __restrict__ boff,
                                              int* __restrict__ row_ptr,
                                              int nb, int M) {
  int l = threadIdx.x;
  int orig = (l < nb) ? bsum[l] : 0;
  int v = orig;
  for (int off = 1; off < 64; off <<= 1) {
    int t = __shfl_up(v, off);
    if (l >= off) v += t;
  }
  if (l < nb) boff[l] = v - orig;
  if (l == nb - 1) row_ptr[M] = v;
}

__global__ __launch_bounds__(256) void k_apply(const int* __restrict__ deg,
                                               const int* __restrict__ boff,
                                               int* __restrict__ row_ptr,
                                               int* __restrict__ cursor, int M) {
  __shared__ int sm[256];
  int tid = threadIdx.x;
  int base = blockIdx.x * 1024 + tid * 4;
  int d[4], p[4];
#pragma unroll
  for (int i = 0; i < 4; ++i) d[i] = (base + i < M) ? deg[base + i] : 0;
  p[0] = 0; p[1] = d[0]; p[2] = d[0] + d[1]; p[3] = d[0] + d[1] + d[2];
  int s = p[3] + d[3];
  sm[tid] = s;
  __syncthreads();
  for (int off = 1; off < 256; off <<= 1) {
    int t = (tid >= off) ? sm[tid - off] : 0;
    __syncthreads();
    sm[tid] += t;
    __syncthreads();
  }
  int excl = sm[tid] - s + boff[blockIdx.x];
#pragma unroll
  for (int i = 0; i < 4; ++i) {
    if (base + i < M) {
      row_ptr[base + i] = excl + p[i];
      cursor[base + i] = excl + p[i];
    }
  }
}

__global__ __launch_bounds__(256) void k_fill(const int* __restrict__ src,
                                              const int* __restrict__ dst,
                                              int* __restrict__ cursor,
                                              int* __restrict__ col, int E) {
  int e = blockIdx.x * 256 + threadIdx.x;
  if (e < E) {
    int p = atomicAdd(&cursor[dst[e]], 1);
    col[p] = src[e];
  }
}

// ---------------- merged fp32 -> split-bf16 conversion (x + 5 weights) --------

__global__ __launch_bounds__(256) void k_splitall(
    const float* __restrict__ x, int nx4, int nxb,
    const float* __restrict__ W1l, const float* __restrict__ W1r,
    const float* __restrict__ W2l, const float* __restrict__ W2r,
    const float* __restrict__ Wm1,
    unsigned short* __restrict__ xh, unsigned short* __restrict__ xl,
    unsigned short* __restrict__ c1h, unsigned short* __restrict__ c1l,
    unsigned short* __restrict__ c2h, unsigned short* __restrict__ c2l,
    unsigned short* __restrict__ m1h, unsigned short* __restrict__ m1l) {
  const float* s; unsigned short* oh; unsigned short* ol; int i, lim;
  int bid = blockIdx.x;
  if (bid < nxb) {
    s = x; oh = xh; ol = xl;
    i = bid * 256 + threadIdx.x; lim = nx4;
  } else {
    int wb = bid - nxb;
    int w = wb >> 6;                       // 64 blocks per 256x256 matrix
    i = (wb & 63) * 256 + threadIdx.x; lim = 16384;
    switch (w) {
      case 0: s = W1l; oh = c1h;         ol = c1l;         break;
      case 1: s = W1r; oh = c1h + 65536; ol = c1l + 65536; break;
      case 2: s = W2l; oh = c2h;         ol = c2l;         break;
      case 3: s = W2r; oh = c2h + 65536; ol = c2l + 65536; break;
      default: s = Wm1; oh = m1h;        ol = m1l;         break;
    }
  }
  if (i >= lim) return;
  float4 v = ((const float4*)s)[i];
  float a[4] = {v.x, v.y, v.z, v.w};
  ushort4v h, l;
#pragma unroll
  for (int j = 0; j < 4; ++j) {
    h[j] = f2bf(a[j]);
    l[j] = f2bf(a[j] - bf2f(h[j]));
  }
  ((ushort4v*)oh)[i] = h;
  ((ushort4v*)ol)[i] = l;
}

// ---------------- split-bf16 MFMA GEMM (round-7 structure, best measured) ----
// C[M, NBF+NF] = (Ah+Al)[M,256] @ (Wh+Wl)[NBF+NF,256]^T  (3-term split product)
// 1-D grid, bijective XCD-chunk swizzle, bx fastest (A-tile L2 reuse).
// Double-buffered LDS with raw s_barrier + counted vmcnt(8).
// bf16 cols get +biasB & relu when biasB != null; f32 cols get +biasF (&relu).

__global__ __launch_bounds__(256) void k_gemm_mfma(
    const unsigned short* __restrict__ Ah, const unsigned short* __restrict__ Al,
    const unsigned short* __restrict__ Wh, const unsigned short* __restrict__ Wl,
    unsigned short* __restrict__ outBF, float* __restrict__ outF32,
    const float* __restrict__ biasF, const float* __restrict__ biasB,
    int M, int NBF, int NF, int relu, int nbxshift) {
  __shared__ char lds[65536];  // 2 buffers x (Ah 8K | Al 8K | Wh 8K | Wl 8K)

  const int tid = threadIdx.x;
  const int wave = tid >> 6;
  const int lane = tid & 63;

  // bijective XCD-chunk swizzle: consecutive logical ids run on one XCD.
  int nwg = gridDim.x;
  int id = blockIdx.x;
  int q = nwg >> 3, r = nwg & 7;
  int xcd = id & 7, j = id >> 3;
  int w = ((xcd < r) ? xcd * (q + 1) : r * (q + 1) + (xcd - r) * q) + j;
  const int by = w >> nbxshift;
  const int bx = w & ((1 << nbxshift) - 1);
  const int n0 = bx * 128;

  // staging: linear LDS dest (base + lane*16), global source pre-permuted
  // so that a read at logical k-slot g uses physical slot g ^ ((row>>1)&3).
  int aoff[2], woff[2], ldso[2];
#pragma unroll
  for (int rr = 0; rr < 2; ++rr) {
    int o = rr * 4096 + wave * 1024 + lane * 16;  // byte offset in tile
    int row = o >> 6;                             // 64 B per row (32 bf16)
    int sp = (o >> 4) & 3;                        // physical 16B slot
    int sl = sp ^ ((row >> 1) & 3);               // logical k-slot stored here
    int arow = by * 128 + row; if (arow > M - 1) arow = M - 1;
    aoff[rr] = arow * 256 + sl * 8;               // elements
    woff[rr] = (n0 + row) * 256 + sl * 8;
    ldso[rr] = rr * 4096 + wave * 1024;           // wave-uniform LDS base
  }

  const int rbase = (wave >> 1) * 64;
  const int cbase = (wave & 1) * 64;
  const int fr = lane & 15;
  const int g = lane >> 4;

  int a_addr[4], w_addr[4];
#pragma unroll
  for (int m = 0; m < 4; ++m) {
    int row = rbase + m * 16 + fr;
    a_addr[m] = row * 64 + ((g ^ ((row >> 1) & 3)) * 16);
  }
#pragma unroll
  for (int n = 0; n < 4; ++n) {
    int row = cbase + n * 16 + fr;
    w_addr[n] = row * 64 + ((g ^ ((row >> 1) & 3)) * 16);
  }

  f32x4 acc[4][4] = {};

  // prologue: stage step 0 into buffer 0
#pragma unroll
  for (int rr = 0; rr < 2; ++rr) {
    GLL16(Ah + aoff[rr], lds + 0     + ldso[rr]);
    GLL16(Al + aoff[rr], lds + 8192  + ldso[rr]);
    GLL16(Wh + woff[rr], lds + 16384 + ldso[rr]);
    GLL16(Wl + woff[rr], lds + 24576 + ldso[rr]);
  }

  for (int t = 0; t < 8; ++t) {
    const int cb = (t & 1) * 32768;        // current buffer
    if (t < 7) {
      const int nbuf = ((t + 1) & 1) * 32768;
      const int ko = (t + 1) * 32;
#pragma unroll
      for (int rr = 0; rr < 2; ++rr) {
        GLL16(Ah + aoff[rr] + ko, lds + nbuf + 0     + ldso[rr]);
        GLL16(Al + aoff[rr] + ko, lds + nbuf + 8192  + ldso[rr]);
        GLL16(Wh + woff[rr] + ko, lds + nbuf + 16384 + ldso[rr]);
        GLL16(Wl + woff[rr] + ko, lds + nbuf + 24576 + ldso[rr]);
      }
      asm volatile("s_waitcnt vmcnt(8)" ::: "memory");  // oldest 8 (cur buf) done
    } else {
      asm volatile("s_waitcnt vmcnt(0)" ::: "memory");
    }
    __builtin_amdgcn_s_barrier();          // all waves' cur-buf loads done

    bf16x8 ah[4], al[4], wh[4], wl[4];
#pragma unroll
    for (int m = 0; m < 4; ++m) {
      ah[m] = *(const bf16x8*)(lds + cb + 0    + a_addr[m]);
      al[m] = *(const bf16x8*)(lds + cb + 8192 + a_addr[m]);
    }
#pragma unroll
    for (int n = 0; n < 4; ++n) {
      wh[n] = *(const bf16x8*)(lds + cb + 16384 + w_addr[n]);
      wl[n] = *(const bf16x8*)(lds + cb + 24576 + w_addr[n]);
    }
#pragma unroll
    for (int m = 0; m < 4; ++m)
#pragma unroll
      for (int n = 0; n < 4; ++n) {
        acc[m][n] = __builtin_amdgcn_mfma_f32_16x16x32_bf16(ah[m], wh[n], acc[m][n], 0, 0, 0);
        acc[m][n] = __builtin_amdgcn_mfma_f32_16x16x32_bf16(ah[m], wl[n], acc[m][n], 0, 0, 0);
        acc[m][n] = __builtin_amdgcn_mfma_f32_16x16x32_bf16(al[m], wh[n], acc[m][n], 0, 0, 0);
      }
    __builtin_amdgcn_s_barrier();          // all waves done reading cur buf
  }

  // epilogue: C/D layout col=lane&15, row=(lane>>4)*4+reg — direct stores
  if (n0 < NBF) {
#pragma unroll
    for (int n = 0; n < 4; ++n) {
      int col = n0 + cbase + n * 16 + fr;
      float bvb = biasB ? biasB[col] : 0.f;
#pragma unroll
      for (int m = 0; m < 4; ++m) {
        f32x4 a = acc[m][n];
#pragma unroll
        for (int rr = 0; rr < 4; ++rr) {
          int row = by * 128 + rbase + m * 16 + g * 4 + rr;
          if (row < M) {
            float v = a[rr] + bvb;
            if (biasB) v = fmaxf(v, 0.f);
            outBF[(size_t)row * NBF + col] = f2bf(v);
          }
        }
      }
    }
  } else {
#pragma unroll
    for (int n = 0; n < 4; ++n) {
      int col = n0 + cbase + n * 16 + fr;
      int fcol = col - NBF;
      float bv = biasF ? biasF[fcol] : 0.f;
#pragma unroll
      for (int m = 0; m < 4; ++m) {
        f32x4 a = acc[m][n];
#pragma unroll
        for (int rr = 0; rr < 4; ++rr) {
          int row = by * 128 + rbase + m * 16 + g * 4 + rr;
          if (row < M) {
            float v = a[rr] + bv;
            if (relu) v = fmaxf(v, 0.f);
            outF32[(size_t)row * NF + fcol] = v;
          }
        }
      }
    }
  }
}

// ---------------- aggregation ----------------
// one wave per node; lanes split in 2 halves; 4-deep unroll -> up to 8
// row-gathers in flight per wave. Combine halves via shfl_xor(32).

__global__ __launch_bounds__(256) void k_agg2(const unsigned short* __restrict__ T1,
                                              const float* __restrict__ T2,
                                              unsigned short* __restrict__ Hh,
                                              unsigned short* __restrict__ Hl,
                                              const int* __restrict__ row_ptr,
                                              const int* __restrict__ col, int M) {
  int wave = threadIdx.x >> 6, lane = threadIdx.x & 63;
  int n = blockIdx.x * 4 + wave;
  if (n >= M) return;
  int beg = row_ptr[n], end = row_ptr[n + 1];
  int half = lane >> 5, sl = lane & 31;
  float s[8] = {0.f, 0.f, 0.f, 0.f, 0.f, 0.f, 0.f, 0.f};
  int j = beg + half;
  for (; j + 6 < end; j += 8) {
    int i0 = col[j];
    int i1 = col[j + 2];
    int i2 = col[j + 4];
    int i3 = col[j + 6];
    ushort8v v0 = *(const ushort8v*)(T1 + (size_t)i0 * 256 + sl * 8);
    ushort8v v1 = *(const ushort8v*)(T1 + (size_t)i1 * 256 + sl * 8);
    ushort8v v2 = *(const ushort8v*)(T1 + (size_t)i2 * 256 + sl * 8);
    ushort8v v3 = *(const ushort8v*)(T1 + (size_t)i3 * 256 + sl * 8);
#pragma unroll
    for (int i = 0; i < 8; ++i)
      s[i] += (bf2f(v0[i]) + bf2f(v1[i])) + (bf2f(v2[i]) + bf2f(v3[i]));
  }
  for (; j < end; j += 2) {
    int i0 = col[j];
    ushort8v v0 = *(const ushort8v*)(T1 + (size_t)i0 * 256 + sl * 8);
#pragma unroll
    for (int i = 0; i < 8; ++i) s[i] += bf2f(v0[i]);
  }
#pragma unroll
  for (int i = 0; i < 8; ++i) s[i] += __shfl_xor(s[i], 32);
  int dg = end - beg;
  float inv = 1.0f / (float)(dg > 0 ? dg : 1);
  const float4* t2p = (const float4*)(T2 + (size_t)n * 256 + sl * 8);
  float4 ta = t2p[0], tb = t2p[1];
  float h[8];
  h[0] = fmaxf(s[0] * inv + ta.x, 0.f);
  h[1] = fmaxf(s[1] * inv + ta.y, 0.f);
  h[2] = fmaxf(s[2] * inv + ta.z, 0.f);
  h[3] = fmaxf(s[3] * inv + ta.w, 0.f);
  h[4] = fmaxf(s[4] * inv + tb.x, 0.f);
  h[5] = fmaxf(s[5] * inv + tb.y, 0.f);
  h[6] = fmaxf(s[6] * inv + tb.z, 0.f);
  h[7] = fmaxf(s[7] * inv + tb.w, 0.f);
  if (half == 0) {
    ushort8v hh;
#pragma unroll
    for (int i = 0; i < 8; ++i) hh[i] = f2bf(h[i]);
    *(ushort8v*)(Hh + (size_t)n * 256 + sl * 8) = hh;
  } else {
    ushort8v hl;
#pragma unroll
    for (int i = 0; i < 8; ++i) {
      unsigned short hi = f2bf(h[i]);
      hl[i] = f2bf(h[i] - bf2f(hi));
    }
    *(ushort8v*)(Hl + (size_t)n * 256 + sl * 8) = hl;
  }
}

// ---------------- final: out = softmax(H_bf16[M,256] @ Wm2[8,256]^T + bm2) ----

__global__ __launch_bounds__(256) void k_final(const unsigned short* __restrict__ H,
                                               const float* __restrict__ Wm2,
                                               const float* __restrict__ bm2,
                                               float* __restrict__ out, int M) {
  int node = blockIdx.x * 4 + (threadIdx.x >> 6);
  int lane = threadIdx.x & 63;
  if (node >= M) return;
  int o = lane >> 3;   // output 0..7
  int r = lane & 7;    // 32-elem k-slice
  const unsigned short* h = H + (size_t)node * D + r * 32;
  const float* w = Wm2 + (size_t)o * D + r * 32;
  float p = 0.f;
#pragma unroll
  for (int c = 0; c < 4; ++c) {
    ushort8v hv = ((const ushort8v*)h)[c];
    float4 w0 = ((const float4*)w)[c * 2];
    float4 w1 = ((const float4*)w)[c * 2 + 1];
    p += bf2f(hv[0]) * w0.x + bf2f(hv[1]) * w0.y + bf2f(hv[2]) * w0.z + bf2f(hv[3]) * w0.w;
    p += bf2f(hv[4]) * w1.x + bf2f(hv[5]) * w1.y + bf2f(hv[6]) * w1.z + bf2f(hv[7]) * w1.w;
  }
  p += __shfl_xor(p, 1);
  p += __shfl_xor(p, 2);
  p += __shfl_xor(p, 4);
  float logit = p + bm2[o];
  float m = logit;
  m = fmaxf(m, __shfl_xor(m, 8));
  m = fmaxf(m, __shfl_xor(m, 16));
  m = fmaxf(m, __shfl_xor(m, 32));
  float e = expf(logit - m);
  float ssum = e;
  ssum += __shfl_xor(ssum, 8);
  ssum += __shfl_xor(ssum, 16);
  ssum += __shfl_xor(ssum, 32);
  if (r == 0) out[(size_t)node * 8 + o] = e / ssum;
}

// ---------------- launch ----------------

extern "C" void kernel_launch(void* const* d_in, const int* in_sizes, int n_in,
                              void* d_out, int out_size, void* d_ws, size_t ws_size,
                              hipStream_t stream) {
  const float* x   = (const float*)d_in[0];
  const int*   ei  = (const int*)d_in[1];
  const float* W1l = (const float*)d_in[2];
  const float* b1  = (const float*)d_in[3];
  const float* W1r = (const float*)d_in[4];
  const float* W2l = (const float*)d_in[5];
  const float* b2  = (const float*)d_in[6];
  const float* W2r = (const float*)d_in[7];
  const float* Wm1 = (const float*)d_in[8];
  const float* bm1 = (const float*)d_in[9];
  const float* Wm2 = (const float*)d_in[10];
  const float* bm2 = (const float*)d_in[11];
  float* out = (float*)d_out;

  int M = in_sizes[0] / D;   // 50000
  int E = in_sizes[1] / 2;   // 800000
  const int* src = ei;
  const int* dst = ei + E;

  char* p = (char*)d_ws;
  auto alloc = [&](size_t bytes) {
    char* q = p;
    p += (bytes + 255) & ~(size_t)255;
    return q;
  };
  unsigned short* bh0  = (unsigned short*)alloc((size_t)M * 256 * 2);  // x/h split hi
  unsigned short* bh1  = (unsigned short*)alloc((size_t)M * 256 * 2);  // x/h split lo
  unsigned short* T1bf = (unsigned short*)alloc((size_t)M * 256 * 2);  // neighbor-path / h3 (bf16)
  float*          T2f  = (float*)alloc((size_t)M * 256 * 4);           // root-path (f32)
  unsigned short* Wc1h = (unsigned short*)alloc(512 * 256 * 2);
  unsigned short* Wc1l = (unsigned short*)alloc(512 * 256 * 2);
  unsigned short* Wc2h = (unsigned short*)alloc(512 * 256 * 2);
  unsigned short* Wc2l = (unsigned short*)alloc(512 * 256 * 2);
  unsigned short* Wm1h = (unsigned short*)alloc(256 * 256 * 2);
  unsigned short* Wm1l = (unsigned short*)alloc(256 * 256 * 2);
  int* deg     = (int*)alloc((size_t)M * 4);
  int* row_ptr = (int*)alloc((size_t)(M + 1) * 4);
  int* cursor  = (int*)alloc((size_t)M * 4);
  int* col     = (int*)alloc((size_t)E * 4);
  int* bsum    = (int*)alloc(64 * 4);
  int* boff    = (int*)alloc(64 * 4);

  int nb = (M + 1023) / 1024;  // 49

  // CSR build (separate small dispatches — grid.sync was 10x worse, r9)
  hipMemsetAsync(deg, 0, (size_t)M * sizeof(int), stream);
  k_deg<<<dim3((E + 255) / 256), dim3(256), 0, stream>>>(dst, deg, E);
  k_bsum<<<dim3(nb), dim3(256), 0, stream>>>(deg, bsum, M);
  k_scanb<<<dim3(1), dim3(64), 0, stream>>>(bsum, boff, row_ptr, nb, M);
  k_apply<<<dim3(nb), dim3(256), 0, stream>>>(deg, boff, row_ptr, cursor, M);
  k_fill<<<dim3((E + 255) / 256), dim3(256), 0, stream>>>(src, dst, cursor, col, E);

  // merged split conversion (x + 5 weight matrices), single dispatch
  int nx4 = M * 256 / 4;               // 3.2M float4
  int nxb = (nx4 + 255) / 256;         // 12500 blocks for x
  k_splitall<<<dim3(nxb + 5 * 64), dim3(256), 0, stream>>>(
      x, nx4, nxb, W1l, W1r, W2l, W2r, Wm1,
      bh0, bh1, Wc1h, Wc1l, Wc2h, Wc2l, Wm1h, Wm1l);

  dim3 blk(256);
  int nwg4 = ((M + 127) / 128) * 4;  // 1564
  int nwg2 = ((M + 127) / 128) * 2;  // 782
  int aggGrid = (M + 3) / 4;

  // Layer 1: [T1 | T2] = x @ [W1l;W1r]^T ; h1 = relu(mean(T1)+T2+b1) -> bh0/bh1
  k_gemm_mfma<<<dim3(nwg4), blk, 0, stream>>>(bh0, bh1, Wc1h, Wc1l, T1bf, T2f,
                                              b1, nullptr, M, 256, 256, 0, 2);
  k_agg2<<<dim3(aggGrid), blk, 0, stream>>>(T1bf, T2f, bh0, bh1, row_ptr, col, M);
  // Layer 2
  k_gemm_mfma<<<dim3(nwg4), blk, 0, stream>>>(bh0, bh1, Wc2h, Wc2l, T1bf, T2f,
                                              b2, nullptr, M, 256, 256, 0, 2);
  k_agg2<<<dim3(aggGrid), blk, 0, stream>>>(T1bf, T2f, bh0, bh1, row_ptr, col, M);
  // MLP: h3 = relu(h2 @ Wm1^T + bm1) -> T1bf (bf16)
  k_gemm_mfma<<<dim3(nwg2), blk, 0, stream>>>(bh0, bh1, Wm1h, Wm1l, T1bf, nullptr,
                                              nullptr, bm1, M, 256, 0, 1, 1);
  // logits + softmax
  k_final<<<dim3((M + 3) / 4), blk, 0, stream>>>(T1bf, Wm2, bm2, out, M);
}